// Round 4
// baseline (903.596 us; speedup 1.0000x reference)
//
#include <hip/hip_runtime.h>

#define BB 4
#define SS 2048
#define DD 1024
#define EE 8
#define HH 2048
#define NTOK (BB*SS)   // 8192 tokens
#define TOT  (NTOK*2)  // 16384 token-slots (top-2)

typedef unsigned short u16;
typedef short s16x8 __attribute__((ext_vector_type(8)));   // 8 bf16 (4 VGPRs)
typedef float f32x4 __attribute__((ext_vector_type(4)));   // 4 fp32 acc

typedef __attribute__((address_space(1))) const void gvoid;
typedef __attribute__((address_space(3))) void lvoid;

__device__ inline u16 f2bf(float f) {
    union { float f; unsigned u; } v; v.f = f;
    unsigned r = v.u + 0x7FFFu + ((v.u >> 16) & 1u);   // RNE
    return (u16)(r >> 16);
}

// async global->LDS, 16B per lane. LDS dest is wave-uniform base + lane*16;
// global src is per-lane. (m97 pattern; dest must be linear/contiguous.)
__device__ inline void gload_lds16(const void* g, void* l) {
    __builtin_amdgcn_global_load_lds((gvoid*)(uintptr_t)g,
                                     (lvoid*)(unsigned)(uintptr_t)l, 16, 0, 0);
}

// ---------------- router: fp32 logits, softmax, top-2, renorm ----------------
__global__ __launch_bounds__(256) void router_kernel(
    const float* __restrict__ x, const float* __restrict__ Wr,
    const float* __restrict__ br, int* __restrict__ tk_e,
    float* __restrict__ tk_w, int* __restrict__ counts)
{
    int wave = threadIdx.x >> 6, lane = threadIdx.x & 63;
    int t = blockIdx.x * 4 + wave;
    const float* xr = x + (size_t)t * DD;
    float acc[8];
    #pragma unroll
    for (int e = 0; e < 8; e++) acc[e] = 0.f;
    #pragma unroll
    for (int c = 0; c < 4; c++) {
        float4 v = *(const float4*)(xr + c * 256 + lane * 4);
        int dbase = c * 256 + lane * 4;
        #pragma unroll
        for (int q = 0; q < 4; q++) {
            float xv = (q == 0) ? v.x : (q == 1) ? v.y : (q == 2) ? v.z : v.w;
            const float4* wr = (const float4*)(Wr + (size_t)(dbase + q) * 8);
            float4 w0 = wr[0], w1 = wr[1];
            acc[0] += xv * w0.x; acc[1] += xv * w0.y;
            acc[2] += xv * w0.z; acc[3] += xv * w0.w;
            acc[4] += xv * w1.x; acc[5] += xv * w1.y;
            acc[6] += xv * w1.z; acc[7] += xv * w1.w;
        }
    }
    #pragma unroll
    for (int off = 32; off > 0; off >>= 1)
        #pragma unroll
        for (int e = 0; e < 8; e++) acc[e] += __shfl_xor(acc[e], off, 64);

    if (lane == 0) {
        float l[8], p[8];
        #pragma unroll
        for (int e = 0; e < 8; e++) l[e] = acc[e] + br[e];
        float mx = l[0];
        #pragma unroll
        for (int e = 1; e < 8; e++) mx = fmaxf(mx, l[e]);
        float s = 0.f;
        #pragma unroll
        for (int e = 0; e < 8; e++) { p[e] = expf(l[e] - mx); s += p[e]; }
        float inv_s = 1.f / s;
        #pragma unroll
        for (int e = 0; e < 8; e++) p[e] *= inv_s;
        int i1 = 0; float p1 = p[0];
        #pragma unroll
        for (int e = 1; e < 8; e++) if (p[e] > p1) { p1 = p[e]; i1 = e; }
        int i2 = -1; float p2 = -1.f;
        #pragma unroll
        for (int e = 0; e < 8; e++) if (e != i1 && p[e] > p2) { p2 = p[e]; i2 = e; }
        float inv = 1.f / (p1 + p2);
        tk_e[2 * t] = i1; tk_e[2 * t + 1] = i2;
        tk_w[2 * t] = p1 * inv; tk_w[2 * t + 1] = p2 * inv;
        atomicAdd(&counts[i1], 1);
        atomicAdd(&counts[i2], 1);
    }
}

__global__ void scan_kernel(const int* __restrict__ counts,
                            int* __restrict__ offs, int* __restrict__ cursors)
{
    if (threadIdx.x == 0) {
        int o = 0;
        for (int e = 0; e < EE; e++) { offs[e] = o; o += counts[e]; }
        offs[EE] = o;
    }
    if (threadIdx.x < EE) cursors[threadIdx.x] = 0;
}

__global__ void scatter_kernel(const int* __restrict__ tk_e,
                               const float* __restrict__ tk_w,
                               const int* __restrict__ offs,
                               int* __restrict__ cursors,
                               int* __restrict__ ent_tok,
                               float* __restrict__ ent_w)
{
    int t = blockIdx.x * blockDim.x + threadIdx.x;
    if (t >= NTOK) return;
    for (int s = 0; s < 2; s++) {
        int e = tk_e[2 * t + s];
        int pos = atomicAdd(&cursors[e], 1);
        int idx = offs[e] + pos;
        ent_tok[idx] = t;
        ent_w[idx] = tk_w[2 * t + s];
    }
}

// gather x rows into packed bf16 Xg [TOT][DD]
__global__ __launch_bounds__(256) void gather_kernel(
    const float* __restrict__ x, const int* __restrict__ ent_tok,
    u16* __restrict__ Xg)
{
    int row = blockIdx.x;
    int t = ent_tok[row];
    const float4* src = (const float4*)(x + (size_t)t * DD);
    ushort4* dst = (ushort4*)(Xg + (size_t)row * DD);
    float4 v = src[threadIdx.x];
    ushort4 o;
    o.x = f2bf(v.x); o.y = f2bf(v.y); o.z = f2bf(v.z); o.w = f2bf(v.w);
    dst[threadIdx.x] = o;
}

// in: [E][R][C] fp32 row-major -> out: [E][C][R] bf16 (transposed)
__global__ __launch_bounds__(256) void transpose_convert(
    const float* __restrict__ in, u16* __restrict__ out, int R, int C)
{
    __shared__ float tile[32][33];
    int e = blockIdx.z;
    const float* src = in + (size_t)e * R * C;
    u16* dst = out + (size_t)e * R * C;
    int c0 = blockIdx.x * 32, r0 = blockIdx.y * 32;
    int tx = threadIdx.x, ty = threadIdx.y;
    #pragma unroll
    for (int i = 0; i < 4; i++)
        tile[ty + i * 8][tx] = src[(size_t)(r0 + ty + i * 8) * C + c0 + tx];
    __syncthreads();
    #pragma unroll
    for (int i = 0; i < 4; i++)
        dst[(size_t)(c0 + ty + i * 8) * R + r0 + tx] = f2bf(tile[tx][ty + i * 8]);
}

// ---------------- grouped GEMM, m97 structure ----------------
// 128x128 tile, 4 waves (2x2), BK=32, global_load_lds staging, builtin MFMA.
// A: packed rows [TOT][KD] bf16. Wt: [E][ND][KD] bf16 (pre-transposed).
// EPI 0: OB = bf16(acc + b)            (H1)
// EPI 1: OB = bf16(silu(acc + b))      (A2)
// EPI 2: out[tok][col] += w*(acc + b)  (final, atomic)
template<int KD, int ND, int EPI>
__global__ __launch_bounds__(256) void gemm_kernel(
    const u16* __restrict__ A, const u16* __restrict__ Wt,
    const float* __restrict__ bias, u16* __restrict__ OB,
    float* __restrict__ out, const int* __restrict__ offs,
    const int* __restrict__ ent_tok, const float* __restrict__ ent_w)
{
    int e = blockIdx.z;
    int mlo = offs[e], mhi = offs[e + 1];
    int m0 = mlo + blockIdx.y * 128;
    if (m0 >= mhi) return;
    int n0 = blockIdx.x * 128;

    __shared__ __align__(16) u16 lA[128 * 32];   // row-major [128][32], linear
    __shared__ __align__(16) u16 lB[128 * 32];

    int tid = threadIdx.x;
    int lane = tid & 63;
    int wave = tid >> 6;
    int wm = wave >> 1, wn = wave & 1;

    // staging: wave w fills 1KB chunks {2w, 2w+1} of lA and lB.
    // chunk c covers rows 16c..16c+15; lane l -> row 16c+(l>>2), k-elems (l&3)*8
    int c0 = wave * 2;
    int lrow = lane >> 2;
    int lk = (lane & 3) * 8;
    int ar0 = m0 + c0 * 16 + lrow;       if (ar0 >= mhi) ar0 = mhi - 1;
    int ar1 = m0 + c0 * 16 + 16 + lrow;  if (ar1 >= mhi) ar1 = mhi - 1;
    const u16* gA0 = A + (size_t)ar0 * KD + lk;
    const u16* gA1 = A + (size_t)ar1 * KD + lk;
    const u16* wb = Wt + (size_t)e * ND * KD;
    const u16* gB0 = wb + (size_t)(n0 + c0 * 16 + lrow) * KD + lk;
    const u16* gB1 = wb + (size_t)(n0 + c0 * 16 + 16 + lrow) * KD + lk;
    u16* sA0 = lA + c0 * 512;   // wave-uniform LDS chunk bases
    u16* sB0 = lB + c0 * 512;

    f32x4 acc[4][4];
    #pragma unroll
    for (int i = 0; i < 4; i++)
        #pragma unroll
        for (int j = 0; j < 4; j++) acc[i][j] = f32x4{0.f, 0.f, 0.f, 0.f};

    for (int k0 = 0; k0 < KD; k0 += 32) {
        __syncthreads();                  // prior tile's reads done
        gload_lds16(gA0 + k0, sA0);
        gload_lds16(gA1 + k0, sA0 + 512);
        gload_lds16(gB0 + k0, sB0);
        gload_lds16(gB1 + k0, sB0 + 512);
        __syncthreads();                  // drains vmcnt(0): tile visible

        s16x8 af[4], bf[4];
        #pragma unroll
        for (int m = 0; m < 4; m++)
            af[m] = *(const s16x8*)(lA + (wm * 64 + m * 16 + (lane & 15)) * 32 + (lane >> 4) * 8);
        #pragma unroll
        for (int n = 0; n < 4; n++)
            bf[n] = *(const s16x8*)(lB + (wn * 64 + n * 16 + (lane & 15)) * 32 + (lane >> 4) * 8);
        #pragma unroll
        for (int m = 0; m < 4; m++)
            #pragma unroll
            for (int n = 0; n < 4; n++)
                acc[m][n] = __builtin_amdgcn_mfma_f32_16x16x32_bf16(af[m], bf[n], acc[m][n], 0, 0, 0);
    }

    const float* bvec = bias + (size_t)e * ND;
    #pragma unroll
    for (int m = 0; m < 4; m++) {
        #pragma unroll
        for (int r = 0; r < 4; r++) {
            int row = m0 + wm * 64 + m * 16 + (lane >> 4) * 4 + r;
            if (row >= mhi) continue;
            if (EPI == 2) {
                int tok = ent_tok[row];
                float w = ent_w[row];
                #pragma unroll
                for (int n = 0; n < 4; n++) {
                    int col = n0 + wn * 64 + n * 16 + (lane & 15);
                    float v = acc[m][n][r] + bvec[col];
                    atomicAdd(&out[(size_t)tok * ND + col], w * v);
                }
            } else {
                #pragma unroll
                for (int n = 0; n < 4; n++) {
                    int col = n0 + wn * 64 + n * 16 + (lane & 15);
                    float v = acc[m][n][r] + bvec[col];
                    if (EPI == 1) v = v / (1.f + expf(-v));   // silu
                    OB[(size_t)row * ND + col] = f2bf(v);
                }
            }
        }
    }
}

extern "C" void kernel_launch(void* const* d_in, const int* in_sizes, int n_in,
                              void* d_out, int out_size, void* d_ws, size_t ws_size,
                              hipStream_t stream) {
    const float* x  = (const float*)d_in[0];
    const float* Wr = (const float*)d_in[1];
    const float* br = (const float*)d_in[2];
    const float* W1 = (const float*)d_in[3];
    const float* b1 = (const float*)d_in[4];
    const float* W2 = (const float*)d_in[5];
    const float* b2 = (const float*)d_in[6];
    const float* W3 = (const float*)d_in[7];
    const float* b3 = (const float*)d_in[8];
    float* out = (float*)d_out;

    char* ws = (char*)d_ws;
    size_t off = 0;
    auto alloc = [&](size_t bytes) {
        char* p = ws + off;
        off = (off + bytes + 255) & ~(size_t)255;
        return p;
    };
    int*   ctrl    = (int*)alloc(256);  // counts[8] | cursors[8] | offs[9]
    int*   counts  = ctrl;
    int*   cursors = ctrl + 8;
    int*   offs    = ctrl + 16;
    int*   tk_e    = (int*)  alloc((size_t)NTOK * 2 * sizeof(int));
    float* tk_w    = (float*)alloc((size_t)NTOK * 2 * sizeof(float));
    int*   ent_tok = (int*)  alloc((size_t)TOT * sizeof(int));
    float* ent_w   = (float*)alloc((size_t)TOT * sizeof(float));
    u16*   Xg      = (u16*)  alloc((size_t)TOT * DD * 2);
    u16*   H1      = (u16*)  alloc((size_t)TOT * HH * 2);
    u16*   A2      = (u16*)  alloc((size_t)TOT * HH * 2);
    u16*   W1t     = (u16*)  alloc((size_t)EE * HH * DD * 2);
    u16*   W2t     = (u16*)  alloc((size_t)EE * HH * HH * 2);
    u16*   W3t     = (u16*)  alloc((size_t)EE * DD * HH * 2);

    hipMemsetAsync(ctrl, 0, 256, stream);
    hipMemsetAsync(out, 0, (size_t)NTOK * DD * sizeof(float), stream);

    dim3 tb(32, 8);
    transpose_convert<<<dim3(HH / 32, DD / 32, EE), tb, 0, stream>>>(W1, W1t, DD, HH);
    transpose_convert<<<dim3(HH / 32, HH / 32, EE), tb, 0, stream>>>(W2, W2t, HH, HH);
    transpose_convert<<<dim3(DD / 32, HH / 32, EE), tb, 0, stream>>>(W3, W3t, HH, DD);

    router_kernel<<<NTOK / 4, 256, 0, stream>>>(x, Wr, br, tk_e, tk_w, counts);
    scan_kernel<<<1, 64, 0, stream>>>(counts, offs, cursors);
    scatter_kernel<<<(NTOK + 255) / 256, 256, 0, stream>>>(tk_e, tk_w, offs, cursors, ent_tok, ent_w);
    gather_kernel<<<TOT, 256, 0, stream>>>(x, ent_tok, Xg);

    gemm_kernel<DD, HH, 0><<<dim3(HH / 128, 64, EE), 256, 0, stream>>>(
        Xg, W1t, b1, H1, nullptr, offs, nullptr, nullptr);
    gemm_kernel<HH, HH, 1><<<dim3(HH / 128, 64, EE), 256, 0, stream>>>(
        H1, W2t, b2, A2, nullptr, offs, nullptr, nullptr);
    gemm_kernel<HH, DD, 2><<<dim3(DD / 128, 64, EE), 256, 0, stream>>>(
        A2, W3t, b3, nullptr, out, offs, ent_tok, ent_w);
}

// Round 5
// 900.878 us; speedup vs baseline: 1.0030x; 1.0030x over previous
//
#include <hip/hip_runtime.h>

#define BB 4
#define SS 2048
#define DD 1024
#define EE 8
#define HH 2048
#define NTOK (BB*SS)   // 8192 tokens
#define TOT  (NTOK*2)  // 16384 token-slots (top-2)

typedef unsigned short u16;
typedef short s16x8 __attribute__((ext_vector_type(8)));   // 8 bf16 (4 VGPRs)
typedef float f32x4 __attribute__((ext_vector_type(4)));   // 4 fp32 acc

typedef __attribute__((address_space(1))) const void gvoid;
typedef __attribute__((address_space(3))) void lvoid;

__device__ inline u16 f2bf(float f) {
    union { float f; unsigned u; } v; v.f = f;
    unsigned r = v.u + 0x7FFFu + ((v.u >> 16) & 1u);   // RNE
    return (u16)(r >> 16);
}

// async global->LDS, 16B per lane. LDS dest is wave-uniform base + lane*16;
// global src is per-lane. (m97 pattern; dest must be linear/contiguous.)
__device__ inline void gload_lds16(const void* g, void* l) {
    __builtin_amdgcn_global_load_lds((gvoid*)(uintptr_t)g,
                                     (lvoid*)(unsigned)(uintptr_t)l, 16, 0, 0);
}

// ---------------- router: fp32 logits, softmax, top-2, renorm ----------------
__global__ __launch_bounds__(256) void router_kernel(
    const float* __restrict__ x, const float* __restrict__ Wr,
    const float* __restrict__ br, int* __restrict__ tk_e,
    float* __restrict__ tk_w, int* __restrict__ counts)
{
    int wave = threadIdx.x >> 6, lane = threadIdx.x & 63;
    int t = blockIdx.x * 4 + wave;
    const float* xr = x + (size_t)t * DD;
    float acc[8];
    #pragma unroll
    for (int e = 0; e < 8; e++) acc[e] = 0.f;
    #pragma unroll
    for (int c = 0; c < 4; c++) {
        float4 v = *(const float4*)(xr + c * 256 + lane * 4);
        int dbase = c * 256 + lane * 4;
        #pragma unroll
        for (int q = 0; q < 4; q++) {
            float xv = (q == 0) ? v.x : (q == 1) ? v.y : (q == 2) ? v.z : v.w;
            const float4* wr = (const float4*)(Wr + (size_t)(dbase + q) * 8);
            float4 w0 = wr[0], w1 = wr[1];
            acc[0] += xv * w0.x; acc[1] += xv * w0.y;
            acc[2] += xv * w0.z; acc[3] += xv * w0.w;
            acc[4] += xv * w1.x; acc[5] += xv * w1.y;
            acc[6] += xv * w1.z; acc[7] += xv * w1.w;
        }
    }
    #pragma unroll
    for (int off = 32; off > 0; off >>= 1)
        #pragma unroll
        for (int e = 0; e < 8; e++) acc[e] += __shfl_xor(acc[e], off, 64);

    if (lane == 0) {
        float l[8], p[8];
        #pragma unroll
        for (int e = 0; e < 8; e++) l[e] = acc[e] + br[e];
        float mx = l[0];
        #pragma unroll
        for (int e = 1; e < 8; e++) mx = fmaxf(mx, l[e]);
        float s = 0.f;
        #pragma unroll
        for (int e = 0; e < 8; e++) { p[e] = expf(l[e] - mx); s += p[e]; }
        float inv_s = 1.f / s;
        #pragma unroll
        for (int e = 0; e < 8; e++) p[e] *= inv_s;
        int i1 = 0; float p1 = p[0];
        #pragma unroll
        for (int e = 1; e < 8; e++) if (p[e] > p1) { p1 = p[e]; i1 = e; }
        int i2 = -1; float p2 = -1.f;
        #pragma unroll
        for (int e = 0; e < 8; e++) if (e != i1 && p[e] > p2) { p2 = p[e]; i2 = e; }
        float inv = 1.f / (p1 + p2);
        tk_e[2 * t] = i1; tk_e[2 * t + 1] = i2;
        tk_w[2 * t] = p1 * inv; tk_w[2 * t + 1] = p2 * inv;
        atomicAdd(&counts[i1], 1);
        atomicAdd(&counts[i2], 1);
    }
}

__global__ void scan_kernel(const int* __restrict__ counts,
                            int* __restrict__ offs, int* __restrict__ cursors)
{
    if (threadIdx.x == 0) {
        int o = 0;
        for (int e = 0; e < EE; e++) { offs[e] = o; o += counts[e]; }
        offs[EE] = o;
    }
    if (threadIdx.x < EE) cursors[threadIdx.x] = 0;
}

__global__ void scatter_kernel(const int* __restrict__ tk_e,
                               const float* __restrict__ tk_w,
                               const int* __restrict__ offs,
                               int* __restrict__ cursors,
                               int* __restrict__ ent_tok,
                               float* __restrict__ ent_w)
{
    int t = blockIdx.x * blockDim.x + threadIdx.x;
    if (t >= NTOK) return;
    for (int s = 0; s < 2; s++) {
        int e = tk_e[2 * t + s];
        int pos = atomicAdd(&cursors[e], 1);
        int idx = offs[e] + pos;
        ent_tok[idx] = t;
        ent_w[idx] = tk_w[2 * t + s];
    }
}

// gather x rows into packed bf16 Xg [TOT][DD]
__global__ __launch_bounds__(256) void gather_kernel(
    const float* __restrict__ x, const int* __restrict__ ent_tok,
    u16* __restrict__ Xg)
{
    int row = blockIdx.x;
    int t = ent_tok[row];
    const float4* src = (const float4*)(x + (size_t)t * DD);
    ushort4* dst = (ushort4*)(Xg + (size_t)row * DD);
    float4 v = src[threadIdx.x];
    ushort4 o;
    o.x = f2bf(v.x); o.y = f2bf(v.y); o.z = f2bf(v.z); o.w = f2bf(v.w);
    dst[threadIdx.x] = o;
}

// in: [E][R][C] fp32 row-major -> out: [E][C][R] bf16 (transposed)
__global__ __launch_bounds__(256) void transpose_convert(
    const float* __restrict__ in, u16* __restrict__ out, int R, int C)
{
    __shared__ float tile[32][33];
    int e = blockIdx.z;
    const float* src = in + (size_t)e * R * C;
    u16* dst = out + (size_t)e * R * C;
    int c0 = blockIdx.x * 32, r0 = blockIdx.y * 32;
    int tx = threadIdx.x, ty = threadIdx.y;
    #pragma unroll
    for (int i = 0; i < 4; i++)
        tile[ty + i * 8][tx] = src[(size_t)(r0 + ty + i * 8) * C + c0 + tx];
    __syncthreads();
    #pragma unroll
    for (int i = 0; i < 4; i++)
        dst[(size_t)(c0 + ty + i * 8) * R + r0 + tx] = f2bf(tile[tx][ty + i * 8]);
}

// ---------------- grouped GEMM, m97 structure ----------------
// 128x128 tile, 4 waves (2x2), BK=32, global_load_lds staging, builtin MFMA.
// A: packed rows [TOT][KD] bf16. Wt: [E][ND][KD] bf16 (pre-transposed).
// EPI 0: OB = bf16(acc + b)            (H1)
// EPI 1: OB = bf16(silu(acc + b))      (A2)
// EPI 2: out[tok][col] += w*(acc + b)  (final, atomic)
template<int KD, int ND, int EPI>
__global__ __launch_bounds__(256) void gemm_kernel(
    const u16* __restrict__ A, const u16* __restrict__ Wt,
    const float* __restrict__ bias, u16* __restrict__ OB,
    float* __restrict__ out, const int* __restrict__ offs,
    const int* __restrict__ ent_tok, const float* __restrict__ ent_w)
{
    int e = blockIdx.z;
    int mlo = offs[e], mhi = offs[e + 1];
    int m0 = mlo + blockIdx.y * 128;
    if (m0 >= mhi) return;
    int n0 = blockIdx.x * 128;

    __shared__ __align__(16) u16 lA[128 * 32];   // row-major [128][32], linear
    __shared__ __align__(16) u16 lB[128 * 32];

    int tid = threadIdx.x;
    int lane = tid & 63;
    int wave = tid >> 6;
    int wm = wave >> 1, wn = wave & 1;

    // staging: wave w fills 1KB chunks {2w, 2w+1} of lA and lB.
    // chunk c covers rows 16c..16c+15; lane l -> row 16c+(l>>2), k-elems (l&3)*8
    int c0 = wave * 2;
    int lrow = lane >> 2;
    int lk = (lane & 3) * 8;
    int ar0 = m0 + c0 * 16 + lrow;       if (ar0 >= mhi) ar0 = mhi - 1;
    int ar1 = m0 + c0 * 16 + 16 + lrow;  if (ar1 >= mhi) ar1 = mhi - 1;
    const u16* gA0 = A + (size_t)ar0 * KD + lk;
    const u16* gA1 = A + (size_t)ar1 * KD + lk;
    const u16* wb = Wt + (size_t)e * ND * KD;
    const u16* gB0 = wb + (size_t)(n0 + c0 * 16 + lrow) * KD + lk;
    const u16* gB1 = wb + (size_t)(n0 + c0 * 16 + 16 + lrow) * KD + lk;
    u16* sA0 = lA + c0 * 512;   // wave-uniform LDS chunk bases
    u16* sB0 = lB + c0 * 512;

    f32x4 acc[4][4];
    #pragma unroll
    for (int i = 0; i < 4; i++)
        #pragma unroll
        for (int j = 0; j < 4; j++) acc[i][j] = f32x4{0.f, 0.f, 0.f, 0.f};

    for (int k0 = 0; k0 < KD; k0 += 32) {
        __syncthreads();                  // prior tile's reads done
        gload_lds16(gA0 + k0, sA0);
        gload_lds16(gA1 + k0, sA0 + 512);
        gload_lds16(gB0 + k0, sB0);
        gload_lds16(gB1 + k0, sB0 + 512);
        __syncthreads();                  // drains vmcnt(0): tile visible

        s16x8 af[4], bf[4];
        #pragma unroll
        for (int m = 0; m < 4; m++)
            af[m] = *(const s16x8*)(lA + (wm * 64 + m * 16 + (lane & 15)) * 32 + (lane >> 4) * 8);
        #pragma unroll
        for (int n = 0; n < 4; n++)
            bf[n] = *(const s16x8*)(lB + (wn * 64 + n * 16 + (lane & 15)) * 32 + (lane >> 4) * 8);
        #pragma unroll
        for (int m = 0; m < 4; m++)
            #pragma unroll
            for (int n = 0; n < 4; n++)
                acc[m][n] = __builtin_amdgcn_mfma_f32_16x16x32_bf16(af[m], bf[n], acc[m][n], 0, 0, 0);
    }

    const float* bvec = bias + (size_t)e * ND;
    #pragma unroll
    for (int m = 0; m < 4; m++) {
        #pragma unroll
        for (int r = 0; r < 4; r++) {
            int row = m0 + wm * 64 + m * 16 + (lane >> 4) * 4 + r;
            if (row >= mhi) continue;
            if (EPI == 2) {
                int tok = ent_tok[row];
                float w = ent_w[row];
                #pragma unroll
                for (int n = 0; n < 4; n++) {
                    int col = n0 + wn * 64 + n * 16 + (lane & 15);
                    float v = acc[m][n][r] + bvec[col];
                    atomicAdd(&out[(size_t)tok * ND + col], w * v);
                }
            } else {
                #pragma unroll
                for (int n = 0; n < 4; n++) {
                    int col = n0 + wn * 64 + n * 16 + (lane & 15);
                    float v = acc[m][n][r] + bvec[col];
                    if (EPI == 1) v = v / (1.f + expf(-v));   // silu
                    OB[(size_t)row * ND + col] = f2bf(v);
                }
            }
        }
    }
}

extern "C" void kernel_launch(void* const* d_in, const int* in_sizes, int n_in,
                              void* d_out, int out_size, void* d_ws, size_t ws_size,
                              hipStream_t stream) {
    const float* x  = (const float*)d_in[0];
    const float* Wr = (const float*)d_in[1];
    const float* br = (const float*)d_in[2];
    const float* W1 = (const float*)d_in[3];
    const float* b1 = (const float*)d_in[4];
    const float* W2 = (const float*)d_in[5];
    const float* b2 = (const float*)d_in[6];
    const float* W3 = (const float*)d_in[7];
    const float* b3 = (const float*)d_in[8];
    float* out = (float*)d_out;

    char* ws = (char*)d_ws;
    size_t off = 0;
    auto alloc = [&](size_t bytes) {
        char* p = ws + off;
        off = (off + bytes + 255) & ~(size_t)255;
        return p;
    };
    int*   ctrl    = (int*)alloc(256);  // counts[8] | cursors[8] | offs[9]
    int*   counts  = ctrl;
    int*   cursors = ctrl + 8;
    int*   offs    = ctrl + 16;
    int*   tk_e    = (int*)  alloc((size_t)NTOK * 2 * sizeof(int));
    float* tk_w    = (float*)alloc((size_t)NTOK * 2 * sizeof(float));
    int*   ent_tok = (int*)  alloc((size_t)TOT * sizeof(int));
    float* ent_w   = (float*)alloc((size_t)TOT * sizeof(float));
    u16*   Xg      = (u16*)  alloc((size_t)TOT * DD * 2);
    u16*   H1      = (u16*)  alloc((size_t)TOT * HH * 2);
    u16*   A2      = (u16*)  alloc((size_t)TOT * HH * 2);
    u16*   W1t     = (u16*)  alloc((size_t)EE * HH * DD * 2);
    u16*   W2t     = (u16*)  alloc((size_t)EE * HH * HH * 2);
    u16*   W3t     = (u16*)  alloc((size_t)EE * DD * HH * 2);

    hipMemsetAsync(ctrl, 0, 256, stream);
    hipMemsetAsync(out, 0, (size_t)NTOK * DD * sizeof(float), stream);

    dim3 tb(32, 8);
    transpose_convert<<<dim3(HH / 32, DD / 32, EE), tb, 0, stream>>>(W1, W1t, DD, HH);
    transpose_convert<<<dim3(HH / 32, HH / 32, EE), tb, 0, stream>>>(W2, W2t, HH, HH);
    transpose_convert<<<dim3(DD / 32, HH / 32, EE), tb, 0, stream>>>(W3, W3t, HH, DD);

    router_kernel<<<NTOK / 4, 256, 0, stream>>>(x, Wr, br, tk_e, tk_w, counts);
    scan_kernel<<<1, 64, 0, stream>>>(counts, offs, cursors);
    scatter_kernel<<<(NTOK + 255) / 256, 256, 0, stream>>>(tk_e, tk_w, offs, cursors, ent_tok, ent_w);
    gather_kernel<<<TOT, 256, 0, stream>>>(x, ent_tok, Xg);

    gemm_kernel<DD, HH, 0><<<dim3(HH / 128, 64, EE), 256, 0, stream>>>(
        Xg, W1t, b1, H1, nullptr, offs, nullptr, nullptr);
    gemm_kernel<HH, HH, 1><<<dim3(HH / 128, 64, EE), 256, 0, stream>>>(
        H1, W2t, b2, A2, nullptr, offs, nullptr, nullptr);
    gemm_kernel<HH, DD, 2><<<dim3(DD / 128, 64, EE), 256, 0, stream>>>(
        A2, W3t, b3, nullptr, out, offs, ent_tok, ent_w);
}

// Round 6
// 867.791 us; speedup vs baseline: 1.0413x; 1.0381x over previous
//
#include <hip/hip_runtime.h>

#define BB 4
#define SS 2048
#define DD 1024
#define EE 8
#define HH 2048
#define NTOK (BB*SS)   // 8192 tokens
#define TOT  (NTOK*2)  // 16384 token-slots (top-2)

typedef unsigned short u16;
typedef short s16x8 __attribute__((ext_vector_type(8)));   // 8 bf16 (4 VGPRs)
typedef float f32x4 __attribute__((ext_vector_type(4)));   // 4 fp32 acc

typedef __attribute__((address_space(1))) const void gvoid;
typedef __attribute__((address_space(3))) void lvoid;

__device__ inline u16 f2bf(float f) {
    union { float f; unsigned u; } v; v.f = f;
    unsigned r = v.u + 0x7FFFu + ((v.u >> 16) & 1u);   // RNE
    return (u16)(r >> 16);
}

// async global->LDS, 16B per lane. LDS dest wave-uniform base + lane*16.
__device__ inline void gload_lds16(const void* g, void* l) {
    __builtin_amdgcn_global_load_lds((gvoid*)(uintptr_t)g,
                                     (lvoid*)(unsigned)(uintptr_t)l, 16, 0, 0);
}

// barrier with compiler memory fence on both sides (keeps ds_read/gload from
// crossing; raw s_barrier builtin alone is not an IR-level memory fence)
#define BARRIER() do { asm volatile("" ::: "memory"); \
    __builtin_amdgcn_s_barrier(); \
    asm volatile("" ::: "memory"); } while (0)

// ---------------- router: fp32 logits, softmax, top-2, renorm ----------------
__global__ __launch_bounds__(256) void router_kernel(
    const float* __restrict__ x, const float* __restrict__ Wr,
    const float* __restrict__ br, int* __restrict__ tk_e,
    float* __restrict__ tk_w, int* __restrict__ counts)
{
    int wave = threadIdx.x >> 6, lane = threadIdx.x & 63;
    int t = blockIdx.x * 4 + wave;
    const float* xr = x + (size_t)t * DD;
    float acc[8];
    #pragma unroll
    for (int e = 0; e < 8; e++) acc[e] = 0.f;
    #pragma unroll
    for (int c = 0; c < 4; c++) {
        float4 v = *(const float4*)(xr + c * 256 + lane * 4);
        int dbase = c * 256 + lane * 4;
        #pragma unroll
        for (int q = 0; q < 4; q++) {
            float xv = (q == 0) ? v.x : (q == 1) ? v.y : (q == 2) ? v.z : v.w;
            const float4* wr = (const float4*)(Wr + (size_t)(dbase + q) * 8);
            float4 w0 = wr[0], w1 = wr[1];
            acc[0] += xv * w0.x; acc[1] += xv * w0.y;
            acc[2] += xv * w0.z; acc[3] += xv * w0.w;
            acc[4] += xv * w1.x; acc[5] += xv * w1.y;
            acc[6] += xv * w1.z; acc[7] += xv * w1.w;
        }
    }
    #pragma unroll
    for (int off = 32; off > 0; off >>= 1)
        #pragma unroll
        for (int e = 0; e < 8; e++) acc[e] += __shfl_xor(acc[e], off, 64);

    if (lane == 0) {
        float l[8], p[8];
        #pragma unroll
        for (int e = 0; e < 8; e++) l[e] = acc[e] + br[e];
        float mx = l[0];
        #pragma unroll
        for (int e = 1; e < 8; e++) mx = fmaxf(mx, l[e]);
        float s = 0.f;
        #pragma unroll
        for (int e = 0; e < 8; e++) { p[e] = expf(l[e] - mx); s += p[e]; }
        float inv_s = 1.f / s;
        #pragma unroll
        for (int e = 0; e < 8; e++) p[e] *= inv_s;
        int i1 = 0; float p1 = p[0];
        #pragma unroll
        for (int e = 1; e < 8; e++) if (p[e] > p1) { p1 = p[e]; i1 = e; }
        int i2 = -1; float p2 = -1.f;
        #pragma unroll
        for (int e = 0; e < 8; e++) if (e != i1 && p[e] > p2) { p2 = p[e]; i2 = e; }
        float inv = 1.f / (p1 + p2);
        tk_e[2 * t] = i1; tk_e[2 * t + 1] = i2;
        tk_w[2 * t] = p1 * inv; tk_w[2 * t + 1] = p2 * inv;
        atomicAdd(&counts[i1], 1);
        atomicAdd(&counts[i2], 1);
    }
}

__global__ void scan_kernel(const int* __restrict__ counts,
                            int* __restrict__ offs, int* __restrict__ cursors)
{
    if (threadIdx.x == 0) {
        int o = 0;
        for (int e = 0; e < EE; e++) { offs[e] = o; o += counts[e]; }
        offs[EE] = o;
    }
    if (threadIdx.x < EE) cursors[threadIdx.x] = 0;
}

__global__ void scatter_kernel(const int* __restrict__ tk_e,
                               const float* __restrict__ tk_w,
                               const int* __restrict__ offs,
                               int* __restrict__ cursors,
                               int* __restrict__ ent_tok,
                               float* __restrict__ ent_w)
{
    int t = blockIdx.x * blockDim.x + threadIdx.x;
    if (t >= NTOK) return;
    for (int s = 0; s < 2; s++) {
        int e = tk_e[2 * t + s];
        int pos = atomicAdd(&cursors[e], 1);
        int idx = offs[e] + pos;
        ent_tok[idx] = t;
        ent_w[idx] = tk_w[2 * t + s];
    }
}

// gather x rows into packed bf16 Xg [TOT][DD]
__global__ __launch_bounds__(256) void gather_kernel(
    const float* __restrict__ x, const int* __restrict__ ent_tok,
    u16* __restrict__ Xg)
{
    int row = blockIdx.x;
    int t = ent_tok[row];
    const float4* src = (const float4*)(x + (size_t)t * DD);
    ushort4* dst = (ushort4*)(Xg + (size_t)row * DD);
    float4 v = src[threadIdx.x];
    ushort4 o;
    o.x = f2bf(v.x); o.y = f2bf(v.y); o.z = f2bf(v.z); o.w = f2bf(v.w);
    dst[threadIdx.x] = o;
}

// in: [E][R][C] fp32 row-major -> out: [E][C][R] bf16 (transposed).
// 64x64 tile, float4 reads, ushort4 writes.
__global__ __launch_bounds__(256) void transpose_convert(
    const float* __restrict__ in, u16* __restrict__ out, int R, int C)
{
    __shared__ u16 tile[64][68];
    int e = blockIdx.z;
    const float* src = in + (size_t)e * R * C;
    u16* dst = out + (size_t)e * R * C;
    int c0 = blockIdx.x * 64, r0 = blockIdx.y * 64;
    int tx = threadIdx.x & 15, ty = threadIdx.x >> 4;
    #pragma unroll
    for (int i = 0; i < 4; i++) {
        int r = i * 16 + ty;
        float4 v = *(const float4*)(src + (size_t)(r0 + r) * C + c0 + tx * 4);
        tile[tx * 4 + 0][r] = f2bf(v.x);
        tile[tx * 4 + 1][r] = f2bf(v.y);
        tile[tx * 4 + 2][r] = f2bf(v.z);
        tile[tx * 4 + 3][r] = f2bf(v.w);
    }
    __syncthreads();
    #pragma unroll
    for (int i = 0; i < 4; i++) {
        int c = i * 16 + ty;
        int r4 = tx * 4;
        ushort4 o = *(const ushort4*)&tile[c][r4];
        *(ushort4*)(dst + (size_t)(c0 + c) * R + r0 + r4) = o;
    }
}

// ---------------- grouped GEMM, 256x256 tile, 8-phase-style schedule --------
// 8 waves (2M x 4N), BK=32, ring-4 LDS buffers, prefetch distance 3 tiles,
// counted vmcnt (10 steady / 8,4,0 peel), XOR-swizzled LDS (write-side via
// pre-swizzled global source, read-side via swizzled ds_read addr), setprio
// around MFMA clusters.
// A: packed rows [TOT][KD] bf16. Wt: [E][ND][KD] bf16 (pre-transposed).
// EPI 0: OB = bf16(acc + b); EPI 1: OB = bf16(silu(acc + b));
// EPI 2: out[tok][col] += w*(acc + b) (atomic).
template<int KD, int ND, int EPI>
__global__ __launch_bounds__(512, 2) void gemm_kernel(
    const u16* __restrict__ A, const u16* __restrict__ Wt,
    const float* __restrict__ bias, u16* __restrict__ OB,
    float* __restrict__ out, const int* __restrict__ offs,
    const int* __restrict__ ent_tok, const float* __restrict__ ent_w)
{
    constexpr int T = KD / 32;            // K-tiles
    static_assert(T >= 4, "need >=4 K-tiles");

    int e = blockIdx.z;
    int mlo = offs[e], mhi = offs[e + 1];
    int m0 = mlo + blockIdx.y * 256;
    if (m0 >= mhi) return;
    int n0 = blockIdx.x * 256;

    // ring of 4 K-tile buffers: [slot][A=0/B=1][256 rows * 32 k] bf16 = 128KB
    __shared__ __align__(16) u16 lds[4][2][256 * 32];

    int tid = threadIdx.x;
    int lane = tid & 63;
    int wave = tid >> 6;
    int wr = wave >> 2, wc = wave & 3;    // 2 x 4 wave grid

    // ---- staging source addresses (write-side swizzle via global source) ----
    // linear LDS dest granule g_dest=tid&3 at row=(j*128+(tid>>2)); content
    // must be natural granule g_dest ^ ((row>>1)&3)  =>  fetch that k-octet.
    int g_nat = ((tid & 3) ^ ((tid >> 3) & 3)) * 8;   // k-elem offset in tile
    int arow0 = m0 + (tid >> 2);       if (arow0 >= mhi) arow0 = mhi - 1;
    int arow1 = m0 + 128 + (tid >> 2); if (arow1 >= mhi) arow1 = mhi - 1;
    const u16* gA0 = A + (size_t)arow0 * KD + g_nat;
    const u16* gA1 = A + (size_t)arow1 * KD + g_nat;
    const u16* wbase = Wt + (size_t)e * ND * KD;
    const u16* gB0 = wbase + (size_t)(n0 + (tid >> 2)) * KD + g_nat;
    const u16* gB1 = wbase + (size_t)(n0 + 128 + (tid >> 2)) * KD + g_nat;

    // ---- fragment read offsets (read-side swizzle), in u16 elems ----
    // row R = base + (lane&15); granule' = (lane>>4) ^ ((R>>1)&3)
    int rsw = (((lane >> 4) ^ (((lane & 15) >> 1) & 3))) * 8;
    int aoff = (wr * 128 + (lane & 15)) * 32 + rsw;
    int boff = (wc * 64 + (lane & 15)) * 32 + rsw;

    f32x4 acc[8][4];
    #pragma unroll
    for (int i = 0; i < 8; i++)
        #pragma unroll
        for (int j = 0; j < 4; j++) acc[i][j] = f32x4{0.f, 0.f, 0.f, 0.f};

    // ---- prologue: stage tiles 0,1,2 (order A(u),B(u) per u) ----
    #pragma unroll
    for (int u = 0; u < 3; u++) {
        u16* dA = &lds[u][0][0] + wave * 512;
        gload_lds16(gA0 + (size_t)u * 32, dA);
        gload_lds16(gA1 + (size_t)u * 32, dA + 4096);
        u16* dB = &lds[u][1][0] + wave * 512;
        gload_lds16(gB0 + (size_t)u * 32, dB);
        gload_lds16(gB1 + (size_t)u * 32, dB + 4096);
    }

    // per-tile body: 2 phases; steady-state stages tile t+3 (A at p0, B at p1)
#define TILE_BODY(t_, NWSTR, STG) do {                                        \
    const u16* sa_ = &lds[(t_) & 3][0][0];                                    \
    const u16* sb_ = &lds[(t_) & 3][1][0];                                    \
    if (STG) {                                                                \
        u16* dA_ = &lds[((t_) + 3) & 3][0][0] + wave * 512;                   \
        gload_lds16(gA0 + (size_t)((t_) + 3) * 32, dA_);                      \
        gload_lds16(gA1 + (size_t)((t_) + 3) * 32, dA_ + 4096);               \
    }                                                                         \
    asm volatile("s_waitcnt vmcnt(" NWSTR ")" ::: "memory");                  \
    BARRIER();                                                                \
    s16x8 af_[4], bq_[4];                                                     \
    _Pragma("unroll")                                                         \
    for (int m_ = 0; m_ < 4; m_++)                                            \
        af_[m_] = *(const s16x8*)(sa_ + aoff + m_ * 512);                     \
    _Pragma("unroll")                                                         \
    for (int n_ = 0; n_ < 4; n_++)                                            \
        bq_[n_] = *(const s16x8*)(sb_ + boff + n_ * 512);                     \
    __builtin_amdgcn_s_setprio(1);                                            \
    _Pragma("unroll")                                                         \
    for (int m_ = 0; m_ < 4; m_++)                                            \
        _Pragma("unroll")                                                     \
        for (int n_ = 0; n_ < 4; n_++)                                        \
            acc[m_][n_] = __builtin_amdgcn_mfma_f32_16x16x32_bf16(            \
                af_[m_], bq_[n_], acc[m_][n_], 0, 0, 0);                      \
    __builtin_amdgcn_s_setprio(0);                                            \
    BARRIER();                                                                \
    _Pragma("unroll")                                                         \
    for (int m_ = 0; m_ < 4; m_++)                                            \
        af_[m_] = *(const s16x8*)(sa_ + aoff + (m_ + 4) * 512);               \
    if (STG) {                                                                \
        u16* dB_ = &lds[((t_) + 3) & 3][1][0] + wave * 512;                   \
        gload_lds16(gB0 + (size_t)((t_) + 3) * 32, dB_);                      \
        gload_lds16(gB1 + (size_t)((t_) + 3) * 32, dB_ + 4096);               \
    }                                                                         \
    BARRIER();                                                                \
    __builtin_amdgcn_s_setprio(1);                                            \
    _Pragma("unroll")                                                         \
    for (int m_ = 0; m_ < 4; m_++)                                            \
        _Pragma("unroll")                                                     \
        for (int n_ = 0; n_ < 4; n_++)                                        \
            acc[m_ + 4][n_] = __builtin_amdgcn_mfma_f32_16x16x32_bf16(        \
                af_[m_], bq_[n_], acc[m_ + 4][n_], 0, 0, 0);                  \
    __builtin_amdgcn_s_setprio(0);                                            \
    BARRIER();                                                                \
} while (0)

    int t = 0;
    for (; t < T - 3; ++t) TILE_BODY(t, "10", 1);
    TILE_BODY(t, "8", 0); ++t;
    TILE_BODY(t, "4", 0); ++t;
    TILE_BODY(t, "0", 0);
#undef TILE_BODY

    // ---- epilogue ----
    const float* bvec = bias + (size_t)e * ND;
    float bv[4];
    #pragma unroll
    for (int n = 0; n < 4; n++)
        bv[n] = bvec[n0 + wc * 64 + n * 16 + (lane & 15)];

    #pragma unroll
    for (int m = 0; m < 8; m++) {
        #pragma unroll
        for (int r = 0; r < 4; r++) {
            int row = m0 + wr * 128 + m * 16 + (lane >> 4) * 4 + r;
            if (row >= mhi) continue;
            if (EPI == 2) {
                int tok = ent_tok[row];
                float w = ent_w[row];
                #pragma unroll
                for (int n = 0; n < 4; n++) {
                    int col = n0 + wc * 64 + n * 16 + (lane & 15);
                    float v = acc[m][n][r] + bv[n];
                    atomicAdd(&out[(size_t)tok * ND + col], w * v);
                }
            } else {
                #pragma unroll
                for (int n = 0; n < 4; n++) {
                    int col = n0 + wc * 64 + n * 16 + (lane & 15);
                    float v = acc[m][n][r] + bv[n];
                    if (EPI == 1) v = v / (1.f + expf(-v));   // silu
                    OB[(size_t)row * ND + col] = f2bf(v);
                }
            }
        }
    }
}

extern "C" void kernel_launch(void* const* d_in, const int* in_sizes, int n_in,
                              void* d_out, int out_size, void* d_ws, size_t ws_size,
                              hipStream_t stream) {
    const float* x  = (const float*)d_in[0];
    const float* Wr = (const float*)d_in[1];
    const float* br = (const float*)d_in[2];
    const float* W1 = (const float*)d_in[3];
    const float* b1 = (const float*)d_in[4];
    const float* W2 = (const float*)d_in[5];
    const float* b2 = (const float*)d_in[6];
    const float* W3 = (const float*)d_in[7];
    const float* b3 = (const float*)d_in[8];
    float* out = (float*)d_out;

    char* ws = (char*)d_ws;
    size_t off = 0;
    auto alloc = [&](size_t bytes) {
        char* p = ws + off;
        off = (off + bytes + 255) & ~(size_t)255;
        return p;
    };
    int*   ctrl    = (int*)alloc(256);  // counts[8] | cursors[8] | offs[9]
    int*   counts  = ctrl;
    int*   cursors = ctrl + 8;
    int*   offs    = ctrl + 16;
    int*   tk_e    = (int*)  alloc((size_t)NTOK * 2 * sizeof(int));
    float* tk_w    = (float*)alloc((size_t)NTOK * 2 * sizeof(float));
    int*   ent_tok = (int*)  alloc((size_t)TOT * sizeof(int));
    float* ent_w   = (float*)alloc((size_t)TOT * sizeof(float));
    u16*   Xg      = (u16*)  alloc((size_t)TOT * DD * 2);
    u16*   H1      = (u16*)  alloc((size_t)TOT * HH * 2);
    u16*   A2      = (u16*)  alloc((size_t)TOT * HH * 2);
    u16*   W1t     = (u16*)  alloc((size_t)EE * HH * DD * 2);
    u16*   W2t     = (u16*)  alloc((size_t)EE * HH * HH * 2);
    u16*   W3t     = (u16*)  alloc((size_t)EE * DD * HH * 2);

    hipMemsetAsync(ctrl, 0, 256, stream);
    hipMemsetAsync(out, 0, (size_t)NTOK * DD * sizeof(float), stream);

    dim3 tb(256);
    transpose_convert<<<dim3(HH / 64, DD / 64, EE), tb, 0, stream>>>(W1, W1t, DD, HH);
    transpose_convert<<<dim3(HH / 64, HH / 64, EE), tb, 0, stream>>>(W2, W2t, HH, HH);
    transpose_convert<<<dim3(DD / 64, HH / 64, EE), tb, 0, stream>>>(W3, W3t, HH, DD);

    router_kernel<<<NTOK / 4, 256, 0, stream>>>(x, Wr, br, tk_e, tk_w, counts);
    scan_kernel<<<1, 64, 0, stream>>>(counts, offs, cursors);
    scatter_kernel<<<(NTOK + 255) / 256, 256, 0, stream>>>(tk_e, tk_w, offs, cursors, ent_tok, ent_w);
    gather_kernel<<<TOT, 256, 0, stream>>>(x, ent_tok, Xg);

    gemm_kernel<DD, HH, 0><<<dim3(HH / 256, TOT / 256, EE), 512, 0, stream>>>(
        Xg, W1t, b1, H1, nullptr, offs, nullptr, nullptr);
    gemm_kernel<HH, HH, 1><<<dim3(HH / 256, TOT / 256, EE), 512, 0, stream>>>(
        H1, W2t, b2, A2, nullptr, offs, nullptr, nullptr);
    gemm_kernel<HH, DD, 2><<<dim3(DD / 256, TOT / 256, EE), 512, 0, stream>>>(
        A2, W3t, b3, nullptr, out, offs, ent_tok, ent_w);
}

// Round 8
// 784.924 us; speedup vs baseline: 1.1512x; 1.1056x over previous
//
#include <hip/hip_runtime.h>

#define BB 4
#define SS 2048
#define DD 1024
#define EE 8
#define HH 2048
#define NTOK (BB*SS)   // 8192 tokens
#define TOT  (NTOK*2)  // 16384 token-slots (top-2)

typedef unsigned short u16;
typedef short s16x8 __attribute__((ext_vector_type(8)));   // 8 bf16 (4 VGPRs)
typedef float f32x4 __attribute__((ext_vector_type(4)));   // 4 fp32 acc

typedef __attribute__((address_space(1))) const void gvoid;
typedef __attribute__((address_space(3))) void lvoid;

__device__ inline u16 f2bf(float f) {
    union { float f; unsigned u; } v; v.f = f;
    unsigned r = v.u + 0x7FFFu + ((v.u >> 16) & 1u);   // RNE
    return (u16)(r >> 16);
}
__device__ inline float bf2f(u16 h) {
    union { unsigned u; float f; } v; v.u = ((unsigned)h) << 16;
    return v.f;
}

// async global->LDS, 16B per lane. LDS dest wave-uniform base + lane*16.
__device__ inline void gload_lds16(const void* g, void* l) {
    __builtin_amdgcn_global_load_lds((gvoid*)(uintptr_t)g,
                                     (lvoid*)(unsigned)(uintptr_t)l, 16, 0, 0);
}

// barrier with compiler memory fences (pin LDS/global ops to their window)
#define BARRIER() do { asm volatile("" ::: "memory"); \
    __builtin_amdgcn_s_barrier(); \
    asm volatile("" ::: "memory"); } while (0)

// ---------------- router: fp32 logits, softmax, top-2, renorm ----------------
__global__ __launch_bounds__(256) void router_kernel(
    const float* __restrict__ x, const float* __restrict__ Wr,
    const float* __restrict__ br, int* __restrict__ tk_e,
    float* __restrict__ tk_w, int* __restrict__ counts)
{
    int wave = threadIdx.x >> 6, lane = threadIdx.x & 63;
    int t = blockIdx.x * 4 + wave;
    const float* xr = x + (size_t)t * DD;
    float acc[8];
    #pragma unroll
    for (int e = 0; e < 8; e++) acc[e] = 0.f;
    #pragma unroll
    for (int c = 0; c < 4; c++) {
        float4 v = *(const float4*)(xr + c * 256 + lane * 4);
        int dbase = c * 256 + lane * 4;
        #pragma unroll
        for (int q = 0; q < 4; q++) {
            float xv = (q == 0) ? v.x : (q == 1) ? v.y : (q == 2) ? v.z : v.w;
            const float4* wr = (const float4*)(Wr + (size_t)(dbase + q) * 8);
            float4 w0 = wr[0], w1 = wr[1];
            acc[0] += xv * w0.x; acc[1] += xv * w0.y;
            acc[2] += xv * w0.z; acc[3] += xv * w0.w;
            acc[4] += xv * w1.x; acc[5] += xv * w1.y;
            acc[6] += xv * w1.z; acc[7] += xv * w1.w;
        }
    }
    #pragma unroll
    for (int off = 32; off > 0; off >>= 1)
        #pragma unroll
        for (int e = 0; e < 8; e++) acc[e] += __shfl_xor(acc[e], off, 64);

    if (lane == 0) {
        float l[8], p[8];
        #pragma unroll
        for (int e = 0; e < 8; e++) l[e] = acc[e] + br[e];
        float mx = l[0];
        #pragma unroll
        for (int e = 1; e < 8; e++) mx = fmaxf(mx, l[e]);
        float s = 0.f;
        #pragma unroll
        for (int e = 0; e < 8; e++) { p[e] = expf(l[e] - mx); s += p[e]; }
        float inv_s = 1.f / s;
        #pragma unroll
        for (int e = 0; e < 8; e++) p[e] *= inv_s;
        int i1 = 0; float p1 = p[0];
        #pragma unroll
        for (int e = 1; e < 8; e++) if (p[e] > p1) { p1 = p[e]; i1 = e; }
        int i2 = -1; float p2 = -1.f;
        #pragma unroll
        for (int e = 0; e < 8; e++) if (e != i1 && p[e] > p2) { p2 = p[e]; i2 = e; }
        float inv = 1.f / (p1 + p2);
        tk_e[2 * t] = i1; tk_e[2 * t + 1] = i2;
        tk_w[2 * t] = p1 * inv; tk_w[2 * t + 1] = p2 * inv;
        atomicAdd(&counts[i1], 1);
        atomicAdd(&counts[i2], 1);
    }
}

__global__ void scan_kernel(const int* __restrict__ counts,
                            int* __restrict__ offs, int* __restrict__ cursors)
{
    if (threadIdx.x == 0) {
        int o = 0;
        for (int e = 0; e < EE; e++) { offs[e] = o; o += counts[e]; }
        offs[EE] = o;
    }
    if (threadIdx.x < EE) cursors[threadIdx.x] = 0;
}

__global__ void scatter_kernel(const int* __restrict__ tk_e,
                               const int* __restrict__ offs,
                               int* __restrict__ cursors,
                               int* __restrict__ ent_tok,
                               int* __restrict__ tok2slot)
{
    int t = blockIdx.x * blockDim.x + threadIdx.x;
    if (t >= NTOK) return;
    for (int s = 0; s < 2; s++) {
        int e = tk_e[2 * t + s];
        int pos = atomicAdd(&cursors[e], 1);
        int idx = offs[e] + pos;
        ent_tok[idx] = t;
        tok2slot[2 * t + s] = idx;
    }
}

// gather x rows into packed bf16 Xg [TOT][DD]
__global__ __launch_bounds__(256) void gather_kernel(
    const float* __restrict__ x, const int* __restrict__ ent_tok,
    u16* __restrict__ Xg)
{
    int row = blockIdx.x;
    int t = ent_tok[row];
    const float4* src = (const float4*)(x + (size_t)t * DD);
    ushort4* dst = (ushort4*)(Xg + (size_t)row * DD);
    float4 v = src[threadIdx.x];
    ushort4 o;
    o.x = f2bf(v.x); o.y = f2bf(v.y); o.z = f2bf(v.z); o.w = f2bf(v.w);
    dst[threadIdx.x] = o;
}

// out[t] = w0*Y[slot0] + w1*Y[slot1]   (Y rows are bf16, already biased)
__global__ __launch_bounds__(256) void combine_kernel(
    const u16* __restrict__ Y, const int* __restrict__ tok2slot,
    const float* __restrict__ tk_w, float* __restrict__ out)
{
    int t = blockIdx.x;
    int s0 = tok2slot[2 * t], s1 = tok2slot[2 * t + 1];
    float w0 = tk_w[2 * t], w1 = tk_w[2 * t + 1];
    const ushort4* r0 = (const ushort4*)(Y + (size_t)s0 * DD);
    const ushort4* r1 = (const ushort4*)(Y + (size_t)s1 * DD);
    ushort4 a = r0[threadIdx.x], b = r1[threadIdx.x];
    float4 o;
    o.x = w0 * bf2f(a.x) + w1 * bf2f(b.x);
    o.y = w0 * bf2f(a.y) + w1 * bf2f(b.y);
    o.z = w0 * bf2f(a.z) + w1 * bf2f(b.z);
    o.w = w0 * bf2f(a.w) + w1 * bf2f(b.w);
    ((float4*)(out + (size_t)t * DD))[threadIdx.x] = o;
}

// in: [E][R][C] fp32 row-major -> out: [E][C][R] bf16 (transposed).
__global__ __launch_bounds__(256) void transpose_convert(
    const float* __restrict__ in, u16* __restrict__ out, int R, int C)
{
    __shared__ u16 tile[64][68];
    int e = blockIdx.z;
    const float* src = in + (size_t)e * R * C;
    u16* dst = out + (size_t)e * R * C;
    int c0 = blockIdx.x * 64, r0 = blockIdx.y * 64;
    int tx = threadIdx.x & 15, ty = threadIdx.x >> 4;
    #pragma unroll
    for (int i = 0; i < 4; i++) {
        int r = i * 16 + ty;
        float4 v = *(const float4*)(src + (size_t)(r0 + r) * C + c0 + tx * 4);
        tile[tx * 4 + 0][r] = f2bf(v.x);
        tile[tx * 4 + 1][r] = f2bf(v.y);
        tile[tx * 4 + 2][r] = f2bf(v.z);
        tile[tx * 4 + 3][r] = f2bf(v.w);
    }
    __syncthreads();
    #pragma unroll
    for (int i = 0; i < 4; i++) {
        int c = i * 16 + ty;
        int r4 = tx * 4;
        ushort4 o = *(const ushort4*)&tile[c][r4];
        *(ushort4*)(dst + (size_t)(c0 + c) * R + r0 + r4) = o;
    }
}

// ---------------- grouped GEMM, 256x256 tile, rotated pipeline (race-fixed) -
// 8 waves (2M x 4N), BK=32, ring-4 LDS slots, prefetch distance 3.
// Hazard rules obeyed:
//  * tile t+1 readable only after {all waves vmcnt covering t+1} -> barrier:
//    vmcnt(8) sits BEFORE BAR_B; reads of t+1 AFTER BAR_B.        (R7 bug fix)
//  * slot WAR: body t stages slot (t+3)%4=(t-1)%4; tile t-1 reads all
//    complete before BAR_A of body t (lgkm waits + rendezvous).
//  * counted lgkm: phase-A operands read one body earlier -> lgkmcnt(4);
//    phase-B operands read early this body -> lgkmcnt(8). sched_barrier(0)
//    after every counted wait (hipcc hoists reg-only MFMA past asm waits).
// EPI 0: OB = bf16(acc + b);  EPI 1: OB = bf16(silu(acc + b)).
template<int KD, int ND, int EPI>
__global__ __launch_bounds__(512, 2) void gemm_kernel(
    const u16* __restrict__ A, const u16* __restrict__ Wt,
    const float* __restrict__ bias, u16* __restrict__ OB,
    const int* __restrict__ offs)
{
    constexpr int T = KD / 32;            // K-tiles (32 or 64; multiple of 4)
    static_assert(T >= 8 && (T % 4) == 0, "T assumptions");

    int e = blockIdx.z;
    int mlo = offs[e], mhi = offs[e + 1];
    int m0 = mlo + blockIdx.y * 256;
    if (m0 >= mhi) return;
    int n0 = blockIdx.x * 256;

    // ring of 4 K-tile slots: [slot][A=0/B=1][256 rows * 32 k] bf16 = 128KB
    __shared__ __align__(16) u16 lds[4][2][256 * 32];

    int tid = threadIdx.x;
    int lane = tid & 63;
    int wave = tid >> 6;
    int wr = wave >> 2, wc = wave & 3;    // 2 x 4 wave grid

    // staging source (write-side swizzle via pre-swizzled global k-octet)
    int g_nat = ((tid & 3) ^ ((tid >> 3) & 3)) * 8;
    int arow0 = m0 + (tid >> 2);       if (arow0 >= mhi) arow0 = mhi - 1;
    int arow1 = m0 + 128 + (tid >> 2); if (arow1 >= mhi) arow1 = mhi - 1;
    const u16* gA0 = A + (size_t)arow0 * KD + g_nat;
    const u16* gA1 = A + (size_t)arow1 * KD + g_nat;
    const u16* wbase = Wt + (size_t)e * ND * KD;
    const u16* gB0 = wbase + (size_t)(n0 + (tid >> 2)) * KD + g_nat;
    const u16* gB1 = wbase + (size_t)(n0 + 128 + (tid >> 2)) * KD + g_nat;

    // fragment read offsets (read-side swizzle), u16 elems
    int rsw = (((lane >> 4) ^ (((lane & 15) >> 1) & 3))) * 8;
    int aoff = (wr * 128 + (lane & 15)) * 32 + rsw;
    int boff = (wc * 64 + (lane & 15)) * 32 + rsw;

    f32x4 acc[8][4];
    #pragma unroll
    for (int i = 0; i < 8; i++)
        #pragma unroll
        for (int j = 0; j < 4; j++) acc[i][j] = f32x4{0.f, 0.f, 0.f, 0.f};

    // prologue: stage tiles 0,1,2 (4 loads per tile, tile-ordered)
    #pragma unroll
    for (int u = 0; u < 3; u++) {
        u16* dA = &lds[u][0][0] + wave * 512;
        u16* dB = &lds[u][1][0] + wave * 512;
        gload_lds16(gA0 + (size_t)u * 32, dA);
        gload_lds16(gA1 + (size_t)u * 32, dA + 4096);
        gload_lds16(gB0 + (size_t)u * 32, dB);
        gload_lds16(gB1 + (size_t)u * 32, dB + 4096);
    }

    s16x8 af1[4], af2[4], bqA[4], bqB[4];
    // tile 0 own loads done (8 newer = tiles 1,2); barrier -> tile 0 safe
    asm volatile("s_waitcnt vmcnt(8)" ::: "memory");
    BARRIER();
    {
        const u16* sa = &lds[0][0][0];
        const u16* sb = &lds[0][1][0];
        #pragma unroll
        for (int m_ = 0; m_ < 4; m_++) af1[m_] = *(const s16x8*)(sa + aoff + m_ * 512);
        #pragma unroll
        for (int n_ = 0; n_ < 4; n_++) bqA[n_] = *(const s16x8*)(sb + boff + n_ * 512);
    }

#define TILE_BODY(t_, BQC, BQN, NWSTR, STG, LAST) do {                        \
    BARRIER();  /* BAR_A: slot (t-1)%4 reads complete in all waves */         \
    const u16* sa_ = &lds[(t_) & 3][0][0];                                    \
    _Pragma("unroll")                                                         \
    for (int m_ = 0; m_ < 4; m_++)                                            \
        af2[m_] = *(const s16x8*)(sa_ + aoff + (m_ + 4) * 512);               \
    if (STG) {                                                                \
        u16* dA_ = &lds[((t_) + 3) & 3][0][0] + wave * 512;                   \
        u16* dB_ = &lds[((t_) + 3) & 3][1][0] + wave * 512;                   \
        gload_lds16(gA0 + (size_t)((t_) + 3) * 32, dA_);                      \
        gload_lds16(gA1 + (size_t)((t_) + 3) * 32, dA_ + 4096);               \
        gload_lds16(gB0 + (size_t)((t_) + 3) * 32, dB_);                      \
        gload_lds16(gB1 + (size_t)((t_) + 3) * 32, dB_ + 4096);               \
    }                                                                         \
    asm volatile("s_waitcnt lgkmcnt(4)" ::: "memory");  /* af1,BQC done */    \
    __builtin_amdgcn_sched_barrier(0);                                        \
    __builtin_amdgcn_s_setprio(1);                                            \
    _Pragma("unroll")                                                         \
    for (int m_ = 0; m_ < 4; m_++)                                            \
        _Pragma("unroll")                                                     \
        for (int n_ = 0; n_ < 4; n_++)                                        \
            acc[m_][n_] = __builtin_amdgcn_mfma_f32_16x16x32_bf16(            \
                af1[m_], BQC[n_], acc[m_][n_], 0, 0, 0);                      \
    __builtin_amdgcn_s_setprio(0);                                            \
    asm volatile("s_waitcnt vmcnt(" NWSTR ")" ::: "memory"); /* t+1 landed */ \
    BARRIER();  /* BAR_B: tile t+1 now safe for ALL waves */                  \
    if (!(LAST)) {                                                            \
        const u16* na_ = &lds[((t_) + 1) & 3][0][0];                          \
        const u16* nb_ = &lds[((t_) + 1) & 3][1][0];                          \
        _Pragma("unroll")                                                     \
        for (int m_ = 0; m_ < 4; m_++)                                        \
            af1[m_] = *(const s16x8*)(na_ + aoff + m_ * 512);                 \
        _Pragma("unroll")                                                     \
        for (int n_ = 0; n_ < 4; n_++)                                        \
            BQN[n_] = *(const s16x8*)(nb_ + boff + n_ * 512);                 \
        asm volatile("s_waitcnt lgkmcnt(8)" ::: "memory");  /* af2 done */    \
    } else {                                                                  \
        asm volatile("s_waitcnt lgkmcnt(0)" ::: "memory");                    \
    }                                                                         \
    __builtin_amdgcn_sched_barrier(0);                                        \
    __builtin_amdgcn_s_setprio(1);                                            \
    _Pragma("unroll")                                                         \
    for (int m_ = 0; m_ < 4; m_++)                                            \
        _Pragma("unroll")                                                     \
        for (int n_ = 0; n_ < 4; n_++)                                        \
            acc[m_ + 4][n_] = __builtin_amdgcn_mfma_f32_16x16x32_bf16(        \
                af2[m_], BQC[n_], acc[m_ + 4][n_], 0, 0, 0);                  \
    __builtin_amdgcn_s_setprio(0);                                            \
} while (0)

    // bodies 0..T-4 stage tile t+3; parity of t picks bq buffer (T%4==0)
    int t = 0;
    for (; t <= T - 6; t += 2) {
        TILE_BODY(t,     bqA, bqB, "8", 1, 0);
        TILE_BODY(t + 1, bqB, bqA, "8", 1, 0);
    }
    TILE_BODY(T - 4, bqA, bqB, "8", 1, 0);   // T-4 even
    TILE_BODY(T - 3, bqB, bqA, "4", 0, 0);   // outstanding: T-2,T-1 -> leave 4
    TILE_BODY(T - 2, bqA, bqB, "0", 0, 0);   // outstanding: T-1 -> drain
    TILE_BODY(T - 1, bqB, bqA, "0", 0, 1);   // last: no next reads
#undef TILE_BODY

    // epilogue: plain bf16 stores
    const float* bvec = bias + (size_t)e * ND;
    float bv[4];
    #pragma unroll
    for (int n = 0; n < 4; n++)
        bv[n] = bvec[n0 + wc * 64 + n * 16 + (lane & 15)];

    #pragma unroll
    for (int m = 0; m < 8; m++) {
        #pragma unroll
        for (int r = 0; r < 4; r++) {
            int row = m0 + wr * 128 + m * 16 + (lane >> 4) * 4 + r;
            if (row >= mhi) continue;
            #pragma unroll
            for (int n = 0; n < 4; n++) {
                int col = n0 + wc * 64 + n * 16 + (lane & 15);
                float v = acc[m][n][r] + bv[n];
                if (EPI == 1) v = v / (1.f + expf(-v));   // silu
                OB[(size_t)row * ND + col] = f2bf(v);
            }
        }
    }
}

extern "C" void kernel_launch(void* const* d_in, const int* in_sizes, int n_in,
                              void* d_out, int out_size, void* d_ws, size_t ws_size,
                              hipStream_t stream) {
    const float* x  = (const float*)d_in[0];
    const float* Wr = (const float*)d_in[1];
    const float* br = (const float*)d_in[2];
    const float* W1 = (const float*)d_in[3];
    const float* b1 = (const float*)d_in[4];
    const float* W2 = (const float*)d_in[5];
    const float* b2 = (const float*)d_in[6];
    const float* W3 = (const float*)d_in[7];
    const float* b3 = (const float*)d_in[8];
    float* out = (float*)d_out;

    char* ws = (char*)d_ws;
    size_t off = 0;
    auto alloc = [&](size_t bytes) {
        char* p = ws + off;
        off = (off + bytes + 255) & ~(size_t)255;
        return p;
    };
    int*   ctrl     = (int*)alloc(256);  // counts[8] | cursors[8] | offs[9]
    int*   counts   = ctrl;
    int*   cursors  = ctrl + 8;
    int*   offs     = ctrl + 16;
    int*   tk_e     = (int*)  alloc((size_t)NTOK * 2 * sizeof(int));
    float* tk_w     = (float*)alloc((size_t)NTOK * 2 * sizeof(float));
    int*   ent_tok  = (int*)  alloc((size_t)TOT * sizeof(int));
    int*   tok2slot = (int*)  alloc((size_t)NTOK * 2 * sizeof(int));
    u16*   Xg       = (u16*)  alloc((size_t)TOT * DD * 2);   // reused as Yg
    u16*   H1       = (u16*)  alloc((size_t)TOT * HH * 2);
    u16*   A2       = (u16*)  alloc((size_t)TOT * HH * 2);
    u16*   W1t      = (u16*)  alloc((size_t)EE * HH * DD * 2);
    u16*   W2t      = (u16*)  alloc((size_t)EE * HH * HH * 2);
    u16*   W3t      = (u16*)  alloc((size_t)EE * DD * HH * 2);

    hipMemsetAsync(ctrl, 0, 256, stream);

    dim3 tb(256);
    transpose_convert<<<dim3(HH / 64, DD / 64, EE), tb, 0, stream>>>(W1, W1t, DD, HH);
    transpose_convert<<<dim3(HH / 64, HH / 64, EE), tb, 0, stream>>>(W2, W2t, HH, HH);
    transpose_convert<<<dim3(DD / 64, HH / 64, EE), tb, 0, stream>>>(W3, W3t, HH, DD);

    router_kernel<<<NTOK / 4, 256, 0, stream>>>(x, Wr, br, tk_e, tk_w, counts);
    scan_kernel<<<1, 64, 0, stream>>>(counts, offs, cursors);
    scatter_kernel<<<(NTOK + 255) / 256, 256, 0, stream>>>(tk_e, offs, cursors, ent_tok, tok2slot);
    gather_kernel<<<TOT, 256, 0, stream>>>(x, ent_tok, Xg);

    gemm_kernel<DD, HH, 0><<<dim3(HH / 256, TOT / 256, EE), 512, 0, stream>>>(
        Xg, W1t, b1, H1, offs);
    gemm_kernel<HH, HH, 1><<<dim3(HH / 256, TOT / 256, EE), 512, 0, stream>>>(
        H1, W2t, b2, A2, offs);
    gemm_kernel<HH, DD, 0><<<dim3(DD / 256, TOT / 256, EE), 512, 0, stream>>>(
        A2, W3t, b3, Xg, offs);   // Yg = Xg (free after GEMM1)

    combine_kernel<<<NTOK, 256, 0, stream>>>(Xg, tok2slot, tk_w, out);
}

// Round 10
// 775.487 us; speedup vs baseline: 1.1652x; 1.0122x over previous
//
#include <hip/hip_runtime.h>

#define BB 4
#define SS 2048
#define DD 1024
#define EE 8
#define HH 2048
#define NTOK (BB*SS)   // 8192 tokens
#define TOT  (NTOK*2)  // 16384 token-slots (top-2)
#define WLMAX (EE + TOT/256)   // 72: max work-list entries (M-blocks of 256)

typedef unsigned short u16;
typedef short s16x8 __attribute__((ext_vector_type(8)));   // 8 bf16 (4 VGPRs)
typedef float f32x4 __attribute__((ext_vector_type(4)));   // 4 fp32 acc

typedef __attribute__((address_space(1))) const void gvoid;
typedef __attribute__((address_space(3))) void lvoid;

__device__ inline u16 f2bf(float f) {
    union { float f; unsigned u; } v; v.f = f;
    unsigned r = v.u + 0x7FFFu + ((v.u >> 16) & 1u);   // RNE
    return (u16)(r >> 16);
}
__device__ inline float bf2f(u16 h) {
    union { unsigned u; float f; } v; v.u = ((unsigned)h) << 16;
    return v.f;
}

// async global->LDS, 16B per lane. LDS dest wave-uniform base + lane*16.
__device__ inline void gload_lds16(const void* g, void* l) {
    __builtin_amdgcn_global_load_lds((gvoid*)(uintptr_t)g,
                                     (lvoid*)(unsigned)(uintptr_t)l, 16, 0, 0);
}

// barrier with compiler memory fences (pin LDS/global ops to their window)
#define BARRIER() do { asm volatile("" ::: "memory"); \
    __builtin_amdgcn_s_barrier(); \
    asm volatile("" ::: "memory"); } while (0)

// ---------------- router: fp32 logits, softmax, top-2, renorm ----------------
__global__ __launch_bounds__(256) void router_kernel(
    const float* __restrict__ x, const float* __restrict__ Wr,
    const float* __restrict__ br, int* __restrict__ tk_e,
    float* __restrict__ tk_w, int* __restrict__ counts)
{
    int wave = threadIdx.x >> 6, lane = threadIdx.x & 63;
    int t = blockIdx.x * 4 + wave;
    const float* xr = x + (size_t)t * DD;
    float acc[8];
    #pragma unroll
    for (int e = 0; e < 8; e++) acc[e] = 0.f;
    #pragma unroll
    for (int c = 0; c < 4; c++) {
        float4 v = *(const float4*)(xr + c * 256 + lane * 4);
        int dbase = c * 256 + lane * 4;
        #pragma unroll
        for (int q = 0; q < 4; q++) {
            float xv = (q == 0) ? v.x : (q == 1) ? v.y : (q == 2) ? v.z : v.w;
            const float4* wr = (const float4*)(Wr + (size_t)(dbase + q) * 8);
            float4 w0 = wr[0], w1 = wr[1];
            acc[0] += xv * w0.x; acc[1] += xv * w0.y;
            acc[2] += xv * w0.z; acc[3] += xv * w0.w;
            acc[4] += xv * w1.x; acc[5] += xv * w1.y;
            acc[6] += xv * w1.z; acc[7] += xv * w1.w;
        }
    }
    #pragma unroll
    for (int off = 32; off > 0; off >>= 1)
        #pragma unroll
        for (int e = 0; e < 8; e++) acc[e] += __shfl_xor(acc[e], off, 64);

    if (lane == 0) {
        float l[8], p[8];
        #pragma unroll
        for (int e = 0; e < 8; e++) l[e] = acc[e] + br[e];
        float mx = l[0];
        #pragma unroll
        for (int e = 1; e < 8; e++) mx = fmaxf(mx, l[e]);
        float s = 0.f;
        #pragma unroll
        for (int e = 0; e < 8; e++) { p[e] = expf(l[e] - mx); s += p[e]; }
        float inv_s = 1.f / s;
        #pragma unroll
        for (int e = 0; e < 8; e++) p[e] *= inv_s;
        int i1 = 0; float p1 = p[0];
        #pragma unroll
        for (int e = 1; e < 8; e++) if (p[e] > p1) { p1 = p[e]; i1 = e; }
        int i2 = -1; float p2 = -1.f;
        #pragma unroll
        for (int e = 0; e < 8; e++) if (e != i1 && p[e] > p2) { p2 = p[e]; i2 = e; }
        float inv = 1.f / (p1 + p2);
        tk_e[2 * t] = i1; tk_e[2 * t + 1] = i2;
        tk_w[2 * t] = p1 * inv; tk_w[2 * t + 1] = p2 * inv;
        atomicAdd(&counts[i1], 1);
        atomicAdd(&counts[i2], 1);
    }
}

// scan + dense work-list build: wl[i] = (expert, mblock) for every 256-row
// M-block of every expert. n_work <= WLMAX.
__global__ void scan_kernel(const int* __restrict__ counts,
                            int* __restrict__ offs, int* __restrict__ cursors,
                            int* __restrict__ wl_e, int* __restrict__ wl_m,
                            int* __restrict__ n_work)
{
    if (threadIdx.x == 0) {
        int o = 0;
        for (int e = 0; e < EE; e++) { offs[e] = o; o += counts[e]; }
        offs[EE] = o;
        int w = 0;
        for (int e = 0; e < EE; e++) {
            int nm = (counts[e] + 255) >> 8;
            for (int m = 0; m < nm; m++) { wl_e[w] = e; wl_m[w] = m; w++; }
        }
        n_work[0] = w;
    }
    if (threadIdx.x < EE) cursors[threadIdx.x] = 0;
}

__global__ void scatter_kernel(const int* __restrict__ tk_e,
                               const int* __restrict__ offs,
                               int* __restrict__ cursors,
                               int* __restrict__ ent_tok,
                               int* __restrict__ tok2slot)
{
    int t = blockIdx.x * blockDim.x + threadIdx.x;
    if (t >= NTOK) return;
    for (int s = 0; s < 2; s++) {
        int e = tk_e[2 * t + s];
        int pos = atomicAdd(&cursors[e], 1);
        int idx = offs[e] + pos;
        ent_tok[idx] = t;
        tok2slot[2 * t + s] = idx;
    }
}

// convert x rows to bf16 Xb [NTOK][DD] (no gather duplication)
__global__ __launch_bounds__(256) void convert_kernel(
    const float* __restrict__ x, u16* __restrict__ Xb)
{
    int row = blockIdx.x;
    const float4* src = (const float4*)(x + (size_t)row * DD);
    ushort4* dst = (ushort4*)(Xb + (size_t)row * DD);
    float4 v = src[threadIdx.x];
    ushort4 o;
    o.x = f2bf(v.x); o.y = f2bf(v.y); o.z = f2bf(v.z); o.w = f2bf(v.w);
    dst[threadIdx.x] = o;
}

// out[t] = w0*Y[slot0] + w1*Y[slot1]   (Y rows are bf16, already biased)
__global__ __launch_bounds__(256) void combine_kernel(
    const u16* __restrict__ Y, const int* __restrict__ tok2slot,
    const float* __restrict__ tk_w, float* __restrict__ out)
{
    int t = blockIdx.x;
    int s0 = tok2slot[2 * t], s1 = tok2slot[2 * t + 1];
    float w0 = tk_w[2 * t], w1 = tk_w[2 * t + 1];
    const ushort4* r0 = (const ushort4*)(Y + (size_t)s0 * DD);
    const ushort4* r1 = (const ushort4*)(Y + (size_t)s1 * DD);
    ushort4 a = r0[threadIdx.x], b = r1[threadIdx.x];
    float4 o;
    o.x = w0 * bf2f(a.x) + w1 * bf2f(b.x);
    o.y = w0 * bf2f(a.y) + w1 * bf2f(b.y);
    o.z = w0 * bf2f(a.z) + w1 * bf2f(b.z);
    o.w = w0 * bf2f(a.w) + w1 * bf2f(b.w);
    ((float4*)(out + (size_t)t * DD))[threadIdx.x] = o;
}

// in: [E][R][C] fp32 row-major -> out: [E][C][R] bf16 (transposed).
// R8-proven version (hardware-verified rounds 6-8): tile stored pre-transposed
// tile[col][row]; 64x64 tile, float4 reads, ushort4 writes.
__global__ __launch_bounds__(256) void transpose_convert(
    const float* __restrict__ in, u16* __restrict__ out, int R, int C)
{
    __shared__ u16 tile[64][68];
    int e = blockIdx.z;
    const float* src = in + (size_t)e * R * C;
    u16* dst = out + (size_t)e * R * C;
    int c0 = blockIdx.x * 64, r0 = blockIdx.y * 64;
    int tx = threadIdx.x & 15, ty = threadIdx.x >> 4;
    #pragma unroll
    for (int i = 0; i < 4; i++) {
        int r = i * 16 + ty;
        float4 v = *(const float4*)(src + (size_t)(r0 + r) * C + c0 + tx * 4);
        tile[tx * 4 + 0][r] = f2bf(v.x);
        tile[tx * 4 + 1][r] = f2bf(v.y);
        tile[tx * 4 + 2][r] = f2bf(v.z);
        tile[tx * 4 + 3][r] = f2bf(v.w);
    }
    __syncthreads();
    #pragma unroll
    for (int i = 0; i < 4; i++) {
        int c = i * 16 + ty;
        int r4 = tx * 4;
        ushort4 o = *(const ushort4*)&tile[c][r4];
        *(ushort4*)(dst + (size_t)(c0 + c) * R + r0 + r4) = o;
    }
}

// ---------------- grouped GEMM, 256x256 tile, rotated pipeline --------------
// 8 waves (2M x 4N), BK=32, ring-4 LDS slots, prefetch distance 3, counted
// vmcnt/lgkm, XOR-swizzled LDS. Work-list indexed: blockIdx.y -> (expert, mblk)
// via dense wl (no empty-block storm). IND: A-rows fetched from Xb via ent_tok
// per-lane source indirection (gload_lds source is per-lane; dest stays linear).
// EPI 0: OB = bf16(acc + b);  EPI 1: OB = bf16(silu(acc + b)).
template<int KD, int ND, int EPI, bool IND>
__global__ __launch_bounds__(512, 2) void gemm_kernel(
    const u16* __restrict__ A, const u16* __restrict__ Wt,
    const float* __restrict__ bias, u16* __restrict__ OB,
    const int* __restrict__ offs, const int* __restrict__ wl_e,
    const int* __restrict__ wl_m, const int* __restrict__ n_work,
    const int* __restrict__ ent_tok)
{
    constexpr int T = KD / 32;            // K-tiles (multiple of 4, >= 8)
    static_assert(T >= 8 && (T % 4) == 0, "T assumptions");

    int wid = blockIdx.y;
    if (wid >= n_work[0]) return;
    int e = wl_e[wid];
    int m0 = offs[e] + wl_m[wid] * 256;
    int mhi = offs[e + 1];
    int n0 = blockIdx.x * 256;

    // ring of 4 K-tile slots: [slot][A=0/B=1][256 rows * 32 k] bf16 = 128KB
    __shared__ __align__(16) u16 lds[4][2][256 * 32];

    int tid = threadIdx.x;
    int lane = tid & 63;
    int wave = tid >> 6;
    int wr = wave >> 2, wc = wave & 3;    // 2 x 4 wave grid

    // staging source (write-side swizzle via pre-swizzled global k-octet)
    int g_nat = ((tid & 3) ^ ((tid >> 3) & 3)) * 8;
    int arow0 = m0 + (tid >> 2);       if (arow0 >= mhi) arow0 = mhi - 1;
    int arow1 = m0 + 128 + (tid >> 2); if (arow1 >= mhi) arow1 = mhi - 1;
    const u16 *gA0, *gA1;
    if (IND) {
        gA0 = A + (size_t)ent_tok[arow0] * KD + g_nat;
        gA1 = A + (size_t)ent_tok[arow1] * KD + g_nat;
    } else {
        gA0 = A + (size_t)arow0 * KD + g_nat;
        gA1 = A + (size_t)arow1 * KD + g_nat;
    }
    const u16* wbase = Wt + (size_t)e * ND * KD;
    const u16* gB0 = wbase + (size_t)(n0 + (tid >> 2)) * KD + g_nat;
    const u16* gB1 = wbase + (size_t)(n0 + 128 + (tid >> 2)) * KD + g_nat;

    // fragment read offsets (read-side swizzle), u16 elems
    int rsw = (((lane >> 4) ^ (((lane & 15) >> 1) & 3))) * 8;
    int aoff = (wr * 128 + (lane & 15)) * 32 + rsw;
    int boff = (wc * 64 + (lane & 15)) * 32 + rsw;

    f32x4 acc[8][4];
    #pragma unroll
    for (int i = 0; i < 8; i++)
        #pragma unroll
        for (int j = 0; j < 4; j++) acc[i][j] = f32x4{0.f, 0.f, 0.f, 0.f};

    // prologue: stage tiles 0,1,2 (4 loads per tile, tile-ordered)
    #pragma unroll
    for (int u = 0; u < 3; u++) {
        u16* dA = &lds[u][0][0] + wave * 512;
        u16* dB = &lds[u][1][0] + wave * 512;
        gload_lds16(gA0 + (size_t)u * 32, dA);
        gload_lds16(gA1 + (size_t)u * 32, dA + 4096);
        gload_lds16(gB0 + (size_t)u * 32, dB);
        gload_lds16(gB1 + (size_t)u * 32, dB + 4096);
    }

    s16x8 af1[4], af2[4], bqA[4], bqB[4];
    // tile 0 own loads done (8 newer = tiles 1,2); barrier -> tile 0 safe
    asm volatile("s_waitcnt vmcnt(8)" ::: "memory");
    BARRIER();
    {
        const u16* sa = &lds[0][0][0];
        const u16* sb = &lds[0][1][0];
        #pragma unroll
        for (int m_ = 0; m_ < 4; m_++) af1[m_] = *(const s16x8*)(sa + aoff + m_ * 512);
        #pragma unroll
        for (int n_ = 0; n_ < 4; n_++) bqA[n_] = *(const s16x8*)(sb + boff + n_ * 512);
    }

#define TILE_BODY(t_, BQC, BQN, NWSTR, STG, LAST) do {                        \
    BARRIER();  /* BAR_A: slot (t-1)%4 reads complete in all waves */         \
    const u16* sa_ = &lds[(t_) & 3][0][0];                                    \
    _Pragma("unroll")                                                         \
    for (int m_ = 0; m_ < 4; m_++)                                            \
        af2[m_] = *(const s16x8*)(sa_ + aoff + (m_ + 4) * 512);               \
    if (STG) {                                                                \
        u16* dA_ = &lds[((t_) + 3) & 3][0][0] + wave * 512;                   \
        u16* dB_ = &lds[((t_) + 3) & 3][1][0] + wave * 512;                   \
        gload_lds16(gA0 + (size_t)((t_) + 3) * 32, dA_);                      \
        gload_lds16(gA1 + (size_t)((t_) + 3) * 32, dA_ + 4096);               \
        gload_lds16(gB0 + (size_t)((t_) + 3) * 32, dB_);                      \
        gload_lds16(gB1 + (size_t)((t_) + 3) * 32, dB_ + 4096);               \
    }                                                                         \
    asm volatile("s_waitcnt lgkmcnt(4)" ::: "memory");  /* af1,BQC done */    \
    __builtin_amdgcn_sched_barrier(0);                                        \
    __builtin_amdgcn_s_setprio(1);                                            \
    _Pragma("unroll")                                                         \
    for (int m_ = 0; m_ < 4; m_++)                                            \
        _Pragma("unroll")                                                     \
        for (int n_ = 0; n_ < 4; n_++)                                        \
            acc[m_][n_] = __builtin_amdgcn_mfma_f32_16x16x32_bf16(            \
                af1[m_], BQC[n_], acc[m_][n_], 0, 0, 0);                      \
    __builtin_amdgcn_s_setprio(0);                                            \
    asm volatile("s_waitcnt vmcnt(" NWSTR ")" ::: "memory"); /* t+1 landed */ \
    BARRIER();  /* BAR_B: tile t+1 now safe for ALL waves */                  \
    if (!(LAST)) {                                                            \
        const u16* na_ = &lds[((t_) + 1) & 3][0][0];                          \
        const u16* nb_ = &lds[((t_) + 1) & 3][1][0];                          \
        _Pragma("unroll")                                                     \
        for (int m_ = 0; m_ < 4; m_++)                                        \
            af1[m_] = *(const s16x8*)(na_ + aoff + m_ * 512);                 \
        _Pragma("unroll")                                                     \
        for (int n_ = 0; n_ < 4; n_++)                                        \
            BQN[n_] = *(const s16x8*)(nb_ + boff + n_ * 512);                 \
        asm volatile("s_waitcnt lgkmcnt(8)" ::: "memory");  /* af2 done */    \
    } else {                                                                  \
        asm volatile("s_waitcnt lgkmcnt(0)" ::: "memory");                    \
    }                                                                         \
    __builtin_amdgcn_sched_barrier(0);                                        \
    __builtin_amdgcn_s_setprio(1);                                            \
    _Pragma("unroll")                                                         \
    for (int m_ = 0; m_ < 4; m_++)                                            \
        _Pragma("unroll")                                                     \
        for (int n_ = 0; n_ < 4; n_++)                                        \
            acc[m_ + 4][n_] = __builtin_amdgcn_mfma_f32_16x16x32_bf16(        \
                af2[m_], BQC[n_], acc[m_ + 4][n_], 0, 0, 0);                  \
    __builtin_amdgcn_s_setprio(0);                                            \
} while (0)

    // bodies 0..T-4 stage tile t+3; parity of t picks bq buffer (T%4==0)
    int t = 0;
    for (; t <= T - 6; t += 2) {
        TILE_BODY(t,     bqA, bqB, "8", 1, 0);
        TILE_BODY(t + 1, bqB, bqA, "8", 1, 0);
    }
    TILE_BODY(T - 4, bqA, bqB, "8", 1, 0);   // T-4 even
    TILE_BODY(T - 3, bqB, bqA, "4", 0, 0);   // outstanding: T-2,T-1 -> leave 4
    TILE_BODY(T - 2, bqA, bqB, "0", 0, 0);   // outstanding: T-1 -> drain
    TILE_BODY(T - 1, bqB, bqA, "0", 0, 1);   // last: no next reads
#undef TILE_BODY

    // epilogue: plain bf16 stores
    const float* bvec = bias + (size_t)e * ND;
    float bv[4];
    #pragma unroll
    for (int n = 0; n < 4; n++)
        bv[n] = bvec[n0 + wc * 64 + n * 16 + (lane & 15)];

    #pragma unroll
    for (int m = 0; m < 8; m++) {
        #pragma unroll
        for (int r = 0; r < 4; r++) {
            int row = m0 + wr * 128 + m * 16 + (lane >> 4) * 4 + r;
            if (row >= mhi) continue;
            #pragma unroll
            for (int n = 0; n < 4; n++) {
                int col = n0 + wc * 64 + n * 16 + (lane & 15);
                float v = acc[m][n][r] + bv[n];
                if (EPI == 1) v = v / (1.f + expf(-v));   // silu
                OB[(size_t)row * ND + col] = f2bf(v);
            }
        }
    }
}

extern "C" void kernel_launch(void* const* d_in, const int* in_sizes, int n_in,
                              void* d_out, int out_size, void* d_ws, size_t ws_size,
                              hipStream_t stream) {
    const float* x  = (const float*)d_in[0];
    const float* Wr = (const float*)d_in[1];
    const float* br = (const float*)d_in[2];
    const float* W1 = (const float*)d_in[3];
    const float* b1 = (const float*)d_in[4];
    const float* W2 = (const float*)d_in[5];
    const float* b2 = (const float*)d_in[6];
    const float* W3 = (const float*)d_in[7];
    const float* b3 = (const float*)d_in[8];
    float* out = (float*)d_out;

    char* ws = (char*)d_ws;
    size_t off = 0;
    auto alloc = [&](size_t bytes) {
        char* p = ws + off;
        off = (off + bytes + 255) & ~(size_t)255;
        return p;
    };
    // ctrl: counts[0:8] cursors[8:16] offs[16:25] n_work[25] wl_e[32:104] wl_m[104:176]
    int*   ctrl     = (int*)alloc(1024);
    int*   counts   = ctrl;
    int*   cursors  = ctrl + 8;
    int*   offs     = ctrl + 16;
    int*   n_work   = ctrl + 25;
    int*   wl_e     = ctrl + 32;
    int*   wl_m     = ctrl + 104;
    int*   tk_e     = (int*)  alloc((size_t)NTOK * 2 * sizeof(int));
    float* tk_w     = (float*)alloc((size_t)NTOK * 2 * sizeof(float));
    int*   ent_tok  = (int*)  alloc((size_t)TOT * sizeof(int));
    int*   tok2slot = (int*)  alloc((size_t)NTOK * 2 * sizeof(int));
    u16*   Xb       = (u16*)  alloc((size_t)NTOK * DD * 2);
    u16*   Yg       = (u16*)  alloc((size_t)TOT * DD * 2);
    u16*   H1       = (u16*)  alloc((size_t)TOT * HH * 2);
    u16*   A2       = (u16*)  alloc((size_t)TOT * HH * 2);
    u16*   W1t      = (u16*)  alloc((size_t)EE * HH * DD * 2);
    u16*   W2t      = (u16*)  alloc((size_t)EE * HH * HH * 2);
    u16*   W3t      = (u16*)  alloc((size_t)EE * DD * HH * 2);

    hipMemsetAsync(ctrl, 0, 1024, stream);

    dim3 tb(256);
    transpose_convert<<<dim3(HH / 64, DD / 64, EE), tb, 0, stream>>>(W1, W1t, DD, HH);
    transpose_convert<<<dim3(HH / 64, HH / 64, EE), tb, 0, stream>>>(W2, W2t, HH, HH);
    transpose_convert<<<dim3(DD / 64, HH / 64, EE), tb, 0, stream>>>(W3, W3t, HH, DD);

    router_kernel<<<NTOK / 4, 256, 0, stream>>>(x, Wr, br, tk_e, tk_w, counts);
    scan_kernel<<<1, 64, 0, stream>>>(counts, offs, cursors, wl_e, wl_m, n_work);
    scatter_kernel<<<(NTOK + 255) / 256, 256, 0, stream>>>(tk_e, offs, cursors, ent_tok, tok2slot);
    convert_kernel<<<NTOK, 256, 0, stream>>>(x, Xb);

    gemm_kernel<DD, HH, 0, true><<<dim3(HH / 256, WLMAX, 1), 512, 0, stream>>>(
        Xb, W1t, b1, H1, offs, wl_e, wl_m, n_work, ent_tok);
    gemm_kernel<HH, HH, 1, false><<<dim3(HH / 256, WLMAX, 1), 512, 0, stream>>>(
        H1, W2t, b2, A2, offs, wl_e, wl_m, n_work, nullptr);
    gemm_kernel<HH, DD, 0, false><<<dim3(DD / 256, WLMAX, 1), 512, 0, stream>>>(
        A2, W3t, b3, Yg, offs, wl_e, wl_m, n_work, nullptr);

    combine_kernel<<<NTOK, 256, 0, stream>>>(Yg, tok2slot, tk_w, out);
}